// Round 1
// baseline (2467.587 us; speedup 1.0000x reference)
//
#include <hip/hip_runtime.h>
#include <hip/hip_bf16.h>

#define DEVI __device__ __forceinline__

typedef __attribute__((ext_vector_type(8))) short short8;
typedef __attribute__((ext_vector_type(4))) float f32x4;
typedef unsigned int u32;
typedef unsigned short u16;

typedef __attribute__((address_space(1))) const u32 gu32_t;
typedef __attribute__((address_space(3))) u32 lu32_t;

DEVI u16 f2bf(float f) {
  u32 u = __builtin_bit_cast(u32, f);
  u32 r = (u + 0x7fffu + ((u >> 16) & 1u)) >> 16;
  return (u16)r;
}

DEVI f32x4 mfma16(short8 a, short8 b, f32x4 c) {
  return __builtin_amdgcn_mfma_f32_16x16x32_bf16(a, b, c, 0, 0, 0);
}

DEVI void gload16(const void* g, void* l) {
  __builtin_amdgcn_global_load_lds((gu32_t*)g, (lu32_t*)l, 16, 0, 0);
}

// ---------------- weight f32 -> bf16 ----------------
__global__ __launch_bounds__(256) void convk(const float* __restrict__ s, u16* __restrict__ d, int n4) {
  int i = blockIdx.x * 256 + threadIdx.x;
  if (i < n4) {
    const float4 v = ((const float4*)s)[i];
    ushort4 o;
    o.x = f2bf(v.x); o.y = f2bf(v.y); o.z = f2bf(v.z); o.w = f2bf(v.w);
    ((ushort4*)d)[i] = o;
  }
}

// ---------------- fused windowed attention ----------------
// one workgroup per window (2048), 256 threads = 4 waves
__global__ __launch_bounds__(256) void attn_kernel(
    const float* __restrict__ x, const float* __restrict__ y,
    const float* __restrict__ g1, const float* __restrict__ b1,
    const float* __restrict__ rpb,
    const u16* __restrict__ wqkv, const float* __restrict__ bqkv,
    const u16* __restrict__ wproj, const float* __restrict__ bproj,
    const float* __restrict__ g2, const float* __restrict__ b2,
    float* __restrict__ out, u16* __restrict__ xn2)
{
  __shared__ __align__(16) u16 sXY[49 * 520];   // LN'd concat window, stride 520 (bank-safe)
  __shared__ __align__(16) u16 sQ[64 * 72];     // q (scaled); later reused as P
  __shared__ __align__(16) u16 sK[64 * 72];     // k; later reused as out_h
  __shared__ __align__(16) u16 sVT[64 * 72];    // v transposed [d][m]
  __shared__ float sRpb[169];

  const int wid = blockIdx.x;
  const int b = wid >> 6, win = wid & 63;
  const int wh = win >> 3, ww = win & 7;
  const int tid = threadIdx.x;
  const int wv = tid >> 6, lane = tid & 63;
  const int rq = lane & 15, kg = lane >> 4;
  const size_t bbase = (size_t)b * (56 * 56);

  // ---- Phase 0: LayerNorm(x), LayerNorm(y) -> sXY (49 x 512 bf16) ----
  const float4 g1v = ((const float4*)g1)[lane];
  const float4 b1v = ((const float4*)b1)[lane];
  for (int j = wv; j < 98; j += 4) {
    const int n = j >> 1, mod = j & 1;
    const int r = n / 7, c = n - r * 7;
    int oh = wh * 7 + r + 3; if (oh >= 56) oh -= 56;  // undo roll(-3)
    int ow = ww * 7 + c + 3; if (ow >= 56) ow -= 56;
    const float* src = (mod ? y : x) + (bbase + oh * 56 + ow) * 256;
    const float4 v = ((const float4*)src)[lane];
    float s = v.x + v.y + v.z + v.w;
    #pragma unroll
    for (int off = 1; off < 64; off <<= 1) s += __shfl_xor(s, off);
    const float mean = s * (1.0f / 256.0f);
    const float dx0 = v.x - mean, dx1 = v.y - mean, dx2 = v.z - mean, dx3 = v.w - mean;
    float sq = dx0 * dx0 + dx1 * dx1 + dx2 * dx2 + dx3 * dx3;
    #pragma unroll
    for (int off = 1; off < 64; off <<= 1) sq += __shfl_xor(sq, off);
    const float rstd = rsqrtf(sq * (1.0f / 256.0f) + 1e-5f);
    ushort4 o;
    o.x = f2bf(dx0 * rstd * g1v.x + b1v.x);
    o.y = f2bf(dx1 * rstd * g1v.y + b1v.y);
    o.z = f2bf(dx2 * rstd * g1v.z + b1v.z);
    o.w = f2bf(dx3 * rstd * g1v.w + b1v.w);
    *(ushort4*)(sXY + n * 520 + mod * 256 + lane * 4) = o;
  }
  __syncthreads();

  f32x4 pacc[16];
  #pragma unroll
  for (int i = 0; i < 16; ++i) pacc[i] = f32x4{0.f, 0.f, 0.f, 0.f};

  const int n0 = wv * 16 + kg * 4;                       // C-layout row base of this lane
  const int arow = (wv * 16 + rq) > 48 ? 48 : (wv * 16 + rq);  // clamped A-frag row
  const bool edge = (wh == 7) || (ww == 7);

  for (int h = 0; h < 8; ++h) {
    if (tid < 169) sRpb[tid] = rpb[tid * 8 + h];

    // ---- QKV: rows [16wv,16wv+16) of q,k,v (each 16x64), K=512 ----
    f32x4 aq[4], ak[4], av[4];
    #pragma unroll
    for (int i = 0; i < 4; ++i) { aq[i] = f32x4{0,0,0,0}; ak[i] = f32x4{0,0,0,0}; av[i] = f32x4{0,0,0,0}; }
    const u16* abase = sXY + arow * 520 + kg * 8;
    const u16* wq0 = wqkv + (size_t)(h * 64 + rq) * 512 + kg * 8;
    #pragma unroll 4
    for (int ks = 0; ks < 16; ++ks) {
      const short8 af = *(const short8*)(abase + ks * 32);
      #pragma unroll
      for (int ct = 0; ct < 4; ++ct) {
        const u16* wr = wq0 + (size_t)(ct * 16) * 512 + ks * 32;
        const short8 bq = *(const short8*)(wr);
        const short8 bk = *(const short8*)(wr + 512 * 512);
        const short8 bv = *(const short8*)(wr + 1024 * 512);
        aq[ct] = mfma16(af, bq, aq[ct]);
        ak[ct] = mfma16(af, bk, ak[ct]);
        av[ct] = mfma16(af, bv, av[ct]);
      }
    }
    #pragma unroll
    for (int ct = 0; ct < 4; ++ct) {
      const int o = ct * 16 + rq;
      const float bq_ = bqkv[h * 64 + o];
      const float bk_ = bqkv[512 + h * 64 + o];
      const float bv_ = bqkv[1024 + h * 64 + o];
      #pragma unroll
      for (int r = 0; r < 4; ++r) {
        sQ[(n0 + r) * 72 + o] = f2bf((aq[ct][r] + bq_) * 0.17677669529663687f);
        sK[(n0 + r) * 72 + o] = f2bf(ak[ct][r] + bk_);
      }
      ushort4 pv4;
      pv4.x = f2bf(av[ct][0] + bv_);
      pv4.y = f2bf(av[ct][1] + bv_);
      pv4.z = f2bf(av[ct][2] + bv_);
      pv4.w = f2bf(av[ct][3] + bv_);
      *(ushort4*)(sVT + o * 72 + n0) = pv4;   // v transposed: [d][m]
    }
    __syncthreads();   // (1) q/k/vT visible to all waves

    // ---- S = q k^T (rows [16wv..) x 64 cols) ----
    f32x4 sacc[4];
    #pragma unroll
    for (int i = 0; i < 4; ++i) sacc[i] = f32x4{0,0,0,0};
    const u16* qbase = sQ + arow * 72 + kg * 8;
    #pragma unroll
    for (int d0 = 0; d0 < 2; ++d0) {
      const short8 qa = *(const short8*)(qbase + d0 * 32);
      #pragma unroll
      for (int ct = 0; ct < 4; ++ct) {
        const int krow = (ct * 16 + rq) > 48 ? 48 : (ct * 16 + rq);
        const short8 kb = *(const short8*)(sK + krow * 72 + d0 * 32 + kg * 8);
        sacc[ct] = mfma16(qa, kb, sacc[ct]);
      }
    }

    // ---- bias + shift-mask + softmax (rows n0..n0+3) ----
    float pv[4][4];
    #pragma unroll
    for (int r = 0; r < 4; ++r) {
      const int n = n0 + r;
      const bool nv = n < 49;
      const int r1 = n / 7, c1 = n - r1 * 7;
      int reg1 = 0;
      if (edge && nv) {
        const int sh1 = wh * 7 + r1, sw1 = ww * 7 + c1;
        reg1 = (sh1 < 49 ? 0 : (sh1 < 53 ? 1 : 2)) * 3 + (sw1 < 49 ? 0 : (sw1 < 53 ? 1 : 2));
      }
      #pragma unroll
      for (int ct = 0; ct < 4; ++ct) {
        const int m = ct * 16 + rq;
        float sv = -1e30f;
        if (nv && m < 49) {
          const int r2 = m / 7, c2 = m - r2 * 7;
          const int rel = (r1 - r2 + 6) * 13 + (c1 - c2 + 6);
          float msk = 0.f;
          if (edge) {
            const int sh2 = wh * 7 + r2, sw2 = ww * 7 + c2;
            const int reg2 = (sh2 < 49 ? 0 : (sh2 < 53 ? 1 : 2)) * 3 + (sw2 < 49 ? 0 : (sw2 < 53 ? 1 : 2));
            msk = (reg1 == reg2) ? 0.f : -100.f;
          }
          sv = sacc[ct][r] + sRpb[rel] + msk;
        }
        pv[r][ct] = sv;
      }
    }
    #pragma unroll
    for (int r = 0; r < 4; ++r) {
      float mx = fmaxf(fmaxf(pv[r][0], pv[r][1]), fmaxf(pv[r][2], pv[r][3]));
      #pragma unroll
      for (int off = 1; off < 16; off <<= 1) mx = fmaxf(mx, __shfl_xor(mx, off));
      float sm = 0.f;
      #pragma unroll
      for (int ct = 0; ct < 4; ++ct) { const float e = __expf(pv[r][ct] - mx); pv[r][ct] = e; sm += e; }
      #pragma unroll
      for (int off = 1; off < 16; off <<= 1) sm += __shfl_xor(sm, off);
      const float inv = 1.0f / sm;
      #pragma unroll
      for (int ct = 0; ct < 4; ++ct)
        sQ[(n0 + r) * 72 + ct * 16 + rq] = f2bf(pv[r][ct] * inv);   // P into own sQ rows
    }

    // ---- PV ----
    f32x4 oacc[4];
    #pragma unroll
    for (int i = 0; i < 4; ++i) oacc[i] = f32x4{0,0,0,0};
    const u16* pbase = sQ + (wv * 16 + rq) * 72 + kg * 8;
    #pragma unroll
    for (int m0 = 0; m0 < 2; ++m0) {
      const short8 pa = *(const short8*)(pbase + m0 * 32);
      #pragma unroll
      for (int ct = 0; ct < 4; ++ct) {
        const short8 vb = *(const short8*)(sVT + (ct * 16 + rq) * 72 + m0 * 32 + kg * 8);
        oacc[ct] = mfma16(pa, vb, oacc[ct]);
      }
    }
    __syncthreads();   // (2) everyone done reading sK / sVT

    // ---- out_h -> sK (own rows), then proj accumulate over this head's 64-dim slice ----
    #pragma unroll
    for (int ct = 0; ct < 4; ++ct) {
      #pragma unroll
      for (int r = 0; r < 4; ++r)
        sK[(n0 + r) * 72 + ct * 16 + rq] = f2bf(oacc[ct][r]);
    }
    const u16* ohb = sK + (wv * 16 + rq) * 72 + kg * 8;
    #pragma unroll
    for (int d0 = 0; d0 < 2; ++d0) {
      const short8 pa = *(const short8*)(ohb + d0 * 32);
      #pragma unroll
      for (int ct = 0; ct < 16; ++ct) {
        const short8 wb = *(const short8*)(wproj + (size_t)(ct * 16 + rq) * 512 + h * 64 + d0 * 32 + kg * 8);
        pacc[ct] = mfma16(pa, wb, pacc[ct]);
      }
    }
  }

  // ---- epilogue: + b_proj + shortcut, write x2, fused LN2 -> xn2 (bf16) ----
  #pragma unroll
  for (int r = 0; r < 4; ++r) {
    const int n = n0 + r;
    if (n >= 49) continue;
    const int rr = n / 7, cc = n - rr * 7;
    int oh = wh * 7 + rr + 3; if (oh >= 56) oh -= 56;
    int ow = ww * 7 + cc + 3; if (ow >= 56) ow -= 56;
    const size_t rowoff = (bbase + oh * 56 + ow) * 256;
    const float* xr = x + rowoff;
    float vals[16];
    float s = 0.f;
    #pragma unroll
    for (int ct = 0; ct < 16; ++ct) {
      const int o = ct * 16 + rq;
      const float v = pacc[ct][r] + bproj[o] + xr[o];
      vals[ct] = v; s += v;
    }
    #pragma unroll
    for (int off = 1; off < 16; off <<= 1) s += __shfl_xor(s, off);
    const float mean = s * (1.0f / 256.0f);
    float sq = 0.f;
    #pragma unroll
    for (int ct = 0; ct < 16; ++ct) { const float d_ = vals[ct] - mean; sq += d_ * d_; }
    #pragma unroll
    for (int off = 1; off < 16; off <<= 1) sq += __shfl_xor(sq, off);
    const float rstd = rsqrtf(sq * (1.0f / 256.0f) + 1e-5f);
    float* orow = out + rowoff;
    u16* xrow = xn2 + rowoff;
    #pragma unroll
    for (int ct = 0; ct < 16; ++ct) {
      const int o = ct * 16 + rq;
      orow[o] = vals[ct];
      xrow[o] = f2bf((vals[ct] - mean) * rstd * g2[o] + b2[o]);
    }
  }
}

// ---------------- MLP GEMMs (m97-style 128x128, BK=64, global_load_lds) ----------------
template<int K, int NOUT, bool GELU>
__global__ __launch_bounds__(256) void mlp_gemm(
    const u16* __restrict__ A, const u16* __restrict__ Bw,
    const float* __restrict__ bias, u16* __restrict__ obf, float* __restrict__ ofr)
{
  __shared__ __align__(16) u16 sA[128 * 64];
  __shared__ __align__(16) u16 sB[128 * 64];
  const int m0 = blockIdx.x * 128;
  const int nn0 = blockIdx.y * 128;
  const int tid = threadIdx.x;
  const int lane = tid & 63;
  const int wv = tid >> 6;
  const int wm = wv >> 1, wn = wv & 1;
  const int rq = lane & 15, kg = lane >> 4;
  f32x4 acc[4][4];
  #pragma unroll
  for (int i = 0; i < 4; ++i)
    #pragma unroll
    for (int j = 0; j < 4; ++j) acc[i][j] = f32x4{0,0,0,0};

  for (int kt = 0; kt < K / 64; ++kt) {
    if (kt) __syncthreads();
    #pragma unroll
    for (int i = 0; i < 4; ++i) {
      const int c = i * 256 + tid;
      gload16(A + (size_t)(m0 + (c >> 3)) * K + kt * 64 + (c & 7) * 8, sA + c * 8);
    }
    #pragma unroll
    for (int i = 0; i < 4; ++i) {
      const int c = i * 256 + tid;
      gload16(Bw + (size_t)(nn0 + (c >> 3)) * K + kt * 64 + (c & 7) * 8, sB + c * 8);
    }
    __syncthreads();
    #pragma unroll
    for (int k0 = 0; k0 < 2; ++k0) {
      short8 af[4], bf8[4];
      #pragma unroll
      for (int mt = 0; mt < 4; ++mt)
        af[mt] = *(const short8*)(sA + (wm * 64 + mt * 16 + rq) * 64 + k0 * 32 + kg * 8);
      #pragma unroll
      for (int nt = 0; nt < 4; ++nt)
        bf8[nt] = *(const short8*)(sB + (wn * 64 + nt * 16 + rq) * 64 + k0 * 32 + kg * 8);
      #pragma unroll
      for (int mt = 0; mt < 4; ++mt)
        #pragma unroll
        for (int nt = 0; nt < 4; ++nt)
          acc[mt][nt] = mfma16(af[mt], bf8[nt], acc[mt][nt]);
    }
  }
  #pragma unroll
  for (int mt = 0; mt < 4; ++mt) {
    #pragma unroll
    for (int nt = 0; nt < 4; ++nt) {
      const int col = nn0 + wn * 64 + nt * 16 + rq;
      const float bcol = bias[col];
      #pragma unroll
      for (int r = 0; r < 4; ++r) {
        const int row = m0 + wm * 64 + mt * 16 + kg * 4 + r;
        float v = acc[mt][nt][r] + bcol;
        if constexpr (GELU) {
          v = 0.5f * v * (1.0f + erff(v * 0.7071067811865476f));
          obf[(size_t)row * NOUT + col] = f2bf(v);
        } else {
          float* p = ofr + (size_t)row * NOUT + col;
          *p = v + *p;   // + bias + residual (x2 already in d_out)
        }
      }
    }
  }
}

extern "C" void kernel_launch(void* const* d_in, const int* in_sizes, int n_in,
                              void* d_out, int out_size, void* d_ws, size_t ws_size,
                              hipStream_t stream) {
  const float* x      = (const float*)d_in[0];
  const float* y      = (const float*)d_in[1];
  const float* g1     = (const float*)d_in[2];
  const float* b1     = (const float*)d_in[3];
  const float* rpb    = (const float*)d_in[4];
  const float* w_qkv  = (const float*)d_in[5];
  const float* b_qkv  = (const float*)d_in[6];
  const float* w_proj = (const float*)d_in[7];
  const float* b_proj = (const float*)d_in[8];
  const float* g2     = (const float*)d_in[9];
  const float* b2     = (const float*)d_in[10];
  const float* w_fc1  = (const float*)d_in[11];
  const float* b_fc1  = (const float*)d_in[12];
  const float* w_fc2  = (const float*)d_in[13];
  const float* b_fc2  = (const float*)d_in[14];
  float* out = (float*)d_out;

  u16* wsp = (u16*)d_ws;
  u16* wqkv_bf  = wsp;                       //  786432 elems
  u16* wproj_bf = wsp + 786432;              //  131072
  u16* wfc1_bf  = wsp + 917504;              //  262144
  u16* wfc2_bf  = wsp + 1179648;             //  262144
  u16* xn2      = wsp + 1441792;             //  25690112 (LN2 output, bf16)
  u16* hbuf     = xn2 + 25690112;            //  25088*1024 per chunk

  convk<<<768, 256, 0, stream>>>(w_qkv,  wqkv_bf,  196608);
  convk<<<128, 256, 0, stream>>>(w_proj, wproj_bf, 32768);
  convk<<<256, 256, 0, stream>>>(w_fc1,  wfc1_bf,  65536);
  convk<<<256, 256, 0, stream>>>(w_fc2,  wfc2_bf,  65536);

  attn_kernel<<<2048, 256, 0, stream>>>(x, y, g1, b1, rpb, wqkv_bf, b_qkv,
                                        wproj_bf, b_proj, g2, b2, out, xn2);

  for (int c = 0; c < 4; ++c) {
    mlp_gemm<256, 1024, true><<<dim3(196, 8), 256, 0, stream>>>(
        xn2 + (size_t)c * 25088 * 256, wfc1_bf, b_fc1, hbuf, nullptr);
    mlp_gemm<1024, 256, false><<<dim3(196, 2), 256, 0, stream>>>(
        hbuf, wfc2_bf, b_fc2, nullptr, out + (size_t)c * 25088 * 256);
  }
}

// Round 2
// 1309.806 us; speedup vs baseline: 1.8839x; 1.8839x over previous
//
#include <hip/hip_runtime.h>
#include <hip/hip_bf16.h>

#define DEVI __device__ __forceinline__

typedef __attribute__((ext_vector_type(8))) short short8;
typedef __attribute__((ext_vector_type(4))) float f32x4;
typedef unsigned int u32;
typedef unsigned short u16;

typedef __attribute__((address_space(1))) const u32 gu32_t;
typedef __attribute__((address_space(3))) u32 lu32_t;

DEVI u16 f2bf(float f) {
  u32 u = __builtin_bit_cast(u32, f);
  u32 r = (u + 0x7fffu + ((u >> 16) & 1u)) >> 16;
  return (u16)r;
}

DEVI f32x4 mfma16(short8 a, short8 b, f32x4 c) {
  return __builtin_amdgcn_mfma_f32_16x16x32_bf16(a, b, c, 0, 0, 0);
}

DEVI void gload16(const void* g, void* l) {
  __builtin_amdgcn_global_load_lds((gu32_t*)g, (lu32_t*)l, 16, 0, 0);
}

#define CHUNK_ROWS 25088   // 512 windows * 49 tokens
#define PLANE ((size_t)CHUNK_ROWS * 64)

// ---------------- weight f32 -> bf16 ----------------
__global__ __launch_bounds__(256) void convk(const float* __restrict__ s, u16* __restrict__ d, int n4) {
  int i = blockIdx.x * 256 + threadIdx.x;
  if (i < n4) {
    const float4 v = ((const float4*)s)[i];
    ushort4 o;
    o.x = f2bf(v.x); o.y = f2bf(v.y); o.z = f2bf(v.z); o.w = f2bf(v.w);
    ((ushort4*)d)[i] = o;
  }
}

// ---------------- LN1 + shift + window gather -> XY bf16 [CHUNK_ROWS][512] ----------------
__global__ __launch_bounds__(256) void ln_gather(
    const float* __restrict__ x, const float* __restrict__ y,
    const float* __restrict__ g1, const float* __restrict__ b1,
    u16* __restrict__ XY, int rowbase)
{
  const int wv = threadIdx.x >> 6, lane = threadIdx.x & 63;
  const int rl = blockIdx.x * 4 + wv;
  const int row = rowbase + rl;
  const int w = row / 49, n = row - w * 49;
  const int b = w >> 6, win = w & 63, wh = win >> 3, ww = win & 7;
  const int r = n / 7, c = n - r * 7;
  int oh = wh * 7 + r + 3; if (oh >= 56) oh -= 56;
  int ow = ww * 7 + c + 3; if (ow >= 56) ow -= 56;
  const size_t po = ((size_t)b * 3136 + oh * 56 + ow) * 256;
  const float4 g1v = ((const float4*)g1)[lane];
  const float4 b1v = ((const float4*)b1)[lane];
  u16* orow = XY + (size_t)rl * 512;
  #pragma unroll
  for (int mod = 0; mod < 2; ++mod) {
    const float* src = (mod ? y : x) + po;
    const float4 v = ((const float4*)src)[lane];
    float s = v.x + v.y + v.z + v.w;
    #pragma unroll
    for (int off = 1; off < 64; off <<= 1) s += __shfl_xor(s, off);
    const float mean = s * (1.0f / 256.0f);
    const float d0 = v.x - mean, d1 = v.y - mean, d2 = v.z - mean, d3 = v.w - mean;
    float sq = d0 * d0 + d1 * d1 + d2 * d2 + d3 * d3;
    #pragma unroll
    for (int off = 1; off < 64; off <<= 1) sq += __shfl_xor(sq, off);
    const float rstd = rsqrtf(sq * (1.0f / 256.0f) + 1e-5f);
    ushort4 o;
    o.x = f2bf(d0 * rstd * g1v.x + b1v.x);
    o.y = f2bf(d1 * rstd * g1v.y + b1v.y);
    o.z = f2bf(d2 * rstd * g1v.z + b1v.z);
    o.w = f2bf(d3 * rstd * g1v.w + b1v.w);
    *(ushort4*)(orow + mod * 256 + lane * 4) = o;
  }
}

// ---------------- QKV GEMM: M=25088, N=1536, K=512; scatter into [t][h][row][64] ----------------
__global__ __launch_bounds__(256) void qkv_gemm(
    const u16* __restrict__ A, const u16* __restrict__ Bw,
    const float* __restrict__ bias, u16* __restrict__ Qo)
{
  __shared__ __align__(16) u16 sA[128 * 64];
  __shared__ __align__(16) u16 sB[128 * 64];
  const int m0 = blockIdx.x * 128;
  const int nn0 = blockIdx.y * 128;
  const int tid = threadIdx.x;
  const int lane = tid & 63;
  const int wv = tid >> 6;
  const int wm = wv >> 1, wn = wv & 1;
  const int rq = lane & 15, kg = lane >> 4;
  f32x4 acc[4][4];
  #pragma unroll
  for (int i = 0; i < 4; ++i)
    #pragma unroll
    for (int j = 0; j < 4; ++j) acc[i][j] = f32x4{0,0,0,0};

  for (int kt = 0; kt < 8; ++kt) {
    if (kt) __syncthreads();
    #pragma unroll
    for (int i = 0; i < 4; ++i) {
      const int c = i * 256 + tid;
      gload16(A + (size_t)(m0 + (c >> 3)) * 512 + kt * 64 + (c & 7) * 8, sA + c * 8);
    }
    #pragma unroll
    for (int i = 0; i < 4; ++i) {
      const int c = i * 256 + tid;
      gload16(Bw + (size_t)(nn0 + (c >> 3)) * 512 + kt * 64 + (c & 7) * 8, sB + c * 8);
    }
    __syncthreads();
    #pragma unroll
    for (int k0 = 0; k0 < 2; ++k0) {
      short8 af[4], bf8[4];
      #pragma unroll
      for (int mt = 0; mt < 4; ++mt)
        af[mt] = *(const short8*)(sA + (wm * 64 + mt * 16 + rq) * 64 + k0 * 32 + kg * 8);
      #pragma unroll
      for (int nt = 0; nt < 4; ++nt)
        bf8[nt] = *(const short8*)(sB + (wn * 64 + nt * 16 + rq) * 64 + k0 * 32 + kg * 8);
      #pragma unroll
      for (int mt = 0; mt < 4; ++mt)
        #pragma unroll
        for (int nt = 0; nt < 4; ++nt)
          acc[mt][nt] = mfma16(af[mt], bf8[nt], acc[mt][nt]);
    }
  }
  #pragma unroll
  for (int mt = 0; mt < 4; ++mt) {
    #pragma unroll
    for (int nt = 0; nt < 4; ++nt) {
      const int col = nn0 + wn * 64 + nt * 16 + rq;
      const int t = col >> 9, rem = col & 511;
      const int h = rem >> 6, d = rem & 63;
      const float bc = bias[col];
      const float sc = (t == 0) ? 0.17677669529663687f : 1.0f;
      u16* bp = Qo + (size_t)(t * 8 + h) * PLANE + d;
      #pragma unroll
      for (int r = 0; r < 4; ++r) {
        const int row = m0 + wm * 64 + mt * 16 + kg * 4 + r;
        bp[(size_t)row * 64] = f2bf((acc[mt][nt][r] + bc) * sc);
      }
    }
  }
}

// ---------------- slim attention + per-head proj accumulate ----------------
// one block per window (512/chunk), 256 thr = 4 waves
__global__ __launch_bounds__(256) void attn2(
    const u16* __restrict__ qkv, const float* __restrict__ rpb,
    const u16* __restrict__ wproj, const float* __restrict__ bproj,
    const float* __restrict__ x, const float* __restrict__ g2, const float* __restrict__ b2,
    float* __restrict__ out, u16* __restrict__ xn2, int wbase)
{
  __shared__ __align__(16) u16 sQ[3136];   // q (swizzled); overlaid by P
  __shared__ __align__(16) u16 sK[3136];   // k (swizzled); overlaid by out_h
  __shared__ __align__(16) u16 sV[3136];   // v (swizzled rows)
  __shared__ __align__(16) u16 sVT[3904];  // v transposed [d][m], stride 60
  __shared__ float sRpb[169];

  const int wl = blockIdx.x;
  const int w = wbase + wl;
  const int b = w >> 6, win = w & 63;
  const int wh = win >> 3, ww = win & 7;
  const int tid = threadIdx.x;
  const int wv = tid >> 6, lane = tid & 63;
  const int rq = lane & 15, kg = lane >> 4;
  const int n0 = wv * 16 + kg * 4;
  const int arow = (wv * 16 + rq) > 48 ? 48 : (wv * 16 + rq);
  const bool edge = (wh == 7) || (ww == 7);

  for (int e = tid; e < 3904; e += 256) sVT[e] = 0;

  f32x4 pacc[16];
  #pragma unroll
  for (int i = 0; i < 16; ++i) pacc[i] = f32x4{0.f, 0.f, 0.f, 0.f};

  for (int h = 0; h < 8; ++h) {
    if (tid < 169) sRpb[tid] = rpb[tid * 8 + h];

    // ---- stage q,k,v (linear LDS dest, pre-swizzled global source) ----
    #pragma unroll
    for (int t3 = 0; t3 < 3; ++t3) {
      const u16* g = qkv + (size_t)(t3 * 8 + h) * PLANE + (size_t)wl * 49 * 64;
      u16* dst = (t3 == 0) ? sQ : (t3 == 1) ? sK : sV;
      #pragma unroll
      for (int i = 0; i < 2; ++i) {
        const int c = tid + i * 256;
        if (c < 392) {
          const int m = c >> 3, s = c & 7;
          const int dc = s ^ (m & 7);
          gload16(g + m * 64 + dc * 8, dst + c * 8);
        }
      }
    }
    __syncthreads();   // B1: staged data visible

    // ---- transpose V -> sVT [d][m] stride 60 ----
    for (int e = tid; e < 3136; e += 256) {
      const int m = e >> 6, d = e & 63;
      sVT[d * 60 + m] = sV[m * 64 + (((d >> 3) ^ (m & 7)) << 3) + (d & 7)];
    }

    // ---- S = q k^T ----
    f32x4 sacc[4];
    #pragma unroll
    for (int i = 0; i < 4; ++i) sacc[i] = f32x4{0,0,0,0};
    #pragma unroll
    for (int d0 = 0; d0 < 2; ++d0) {
      const short8 qa = *(const short8*)(sQ + arow * 64 + (((d0 * 4 + kg) ^ (arow & 7)) << 3));
      #pragma unroll
      for (int ct = 0; ct < 4; ++ct) {
        const int krow = (ct * 16 + rq) > 48 ? 48 : (ct * 16 + rq);
        const short8 kb = *(const short8*)(sK + krow * 64 + (((d0 * 4 + kg) ^ (krow & 7)) << 3));
        sacc[ct] = mfma16(qa, kb, sacc[ct]);
      }
    }

    // ---- bias + shift-mask + softmax; P -> sQ (swizzled, own rows) ----
    float pv[4][4];
    #pragma unroll
    for (int r = 0; r < 4; ++r) {
      const int n = n0 + r;
      const bool nv = n < 49;
      const int r1 = n / 7, c1 = n - r1 * 7;
      int reg1 = 0;
      if (edge && nv) {
        const int sh1 = wh * 7 + r1, sw1 = ww * 7 + c1;
        reg1 = (sh1 < 49 ? 0 : (sh1 < 53 ? 1 : 2)) * 3 + (sw1 < 49 ? 0 : (sw1 < 53 ? 1 : 2));
      }
      #pragma unroll
      for (int ct = 0; ct < 4; ++ct) {
        const int m = ct * 16 + rq;
        float sv = -1e30f;
        if (nv && m < 49) {
          const int r2 = m / 7, c2 = m - r2 * 7;
          const int rel = (r1 - r2 + 6) * 13 + (c1 - c2 + 6);
          float msk = 0.f;
          if (edge) {
            const int sh2 = wh * 7 + r2, sw2 = ww * 7 + c2;
            const int reg2 = (sh2 < 49 ? 0 : (sh2 < 53 ? 1 : 2)) * 3 + (sw2 < 49 ? 0 : (sw2 < 53 ? 1 : 2));
            msk = (reg1 == reg2) ? 0.f : -100.f;
          }
          sv = sacc[ct][r] + sRpb[rel] + msk;
        }
        pv[r][ct] = sv;
      }
    }
    #pragma unroll
    for (int r = 0; r < 4; ++r) {
      const int n = n0 + r;
      float mx = fmaxf(fmaxf(pv[r][0], pv[r][1]), fmaxf(pv[r][2], pv[r][3]));
      #pragma unroll
      for (int off = 1; off < 16; off <<= 1) mx = fmaxf(mx, __shfl_xor(mx, off));
      float sm = 0.f;
      #pragma unroll
      for (int ct = 0; ct < 4; ++ct) { const float e = __expf(pv[r][ct] - mx); pv[r][ct] = e; sm += e; }
      #pragma unroll
      for (int off = 1; off < 16; off <<= 1) sm += __shfl_xor(sm, off);
      const float inv = 1.0f / sm;
      if (n < 49) {
        #pragma unroll
        for (int ct = 0; ct < 4; ++ct) {
          const int col = ct * 16 + rq;
          sQ[n * 64 + (((col >> 3) ^ (n & 7)) << 3) + (col & 7)] = f2bf(pv[r][ct] * inv);
        }
      }
    }
    __syncthreads();   // B2: sVT complete; all waves past S (sK reads done)

    // ---- PV ----
    f32x4 oacc[4];
    #pragma unroll
    for (int i = 0; i < 4; ++i) oacc[i] = f32x4{0,0,0,0};
    #pragma unroll
    for (int m0 = 0; m0 < 2; ++m0) {
      const short8 pa = *(const short8*)(sQ + arow * 64 + (((m0 * 4 + kg) ^ (arow & 7)) << 3));
      #pragma unroll
      for (int ct = 0; ct < 4; ++ct) {
        const short8 vb = *(const short8*)(sVT + (ct * 16 + rq) * 60 + m0 * 32 + kg * 8);
        oacc[ct] = mfma16(pa, vb, oacc[ct]);
      }
    }

    // ---- out_h -> sK (own rows, swizzled), proj accumulate ----
    #pragma unroll
    for (int ct = 0; ct < 4; ++ct) {
      #pragma unroll
      for (int r = 0; r < 4; ++r) {
        const int n = n0 + r;
        if (n < 49) {
          const int col = ct * 16 + rq;
          sK[n * 64 + (((col >> 3) ^ (n & 7)) << 3) + (col & 7)] = f2bf(oacc[ct][r]);
        }
      }
    }
    #pragma unroll
    for (int d0 = 0; d0 < 2; ++d0) {
      const short8 oa = *(const short8*)(sK + arow * 64 + (((d0 * 4 + kg) ^ (arow & 7)) << 3));
      #pragma unroll
      for (int ct = 0; ct < 16; ++ct) {
        const short8 wb = *(const short8*)(wproj + (size_t)(ct * 16 + rq) * 512 + h * 64 + d0 * 32 + kg * 8);
        pacc[ct] = mfma16(oa, wb, pacc[ct]);
      }
    }
    __syncthreads();   // B3: safe to restage
  }

  // ---- epilogue: + b_proj + shortcut, write x2, fused LN2 -> xn2 ----
  const size_t bbase = (size_t)b * 3136;
  #pragma unroll
  for (int r = 0; r < 4; ++r) {
    const int n = n0 + r;
    if (n >= 49) continue;
    const int rr = n / 7, cc = n - rr * 7;
    int oh = wh * 7 + rr + 3; if (oh >= 56) oh -= 56;
    int ow = ww * 7 + cc + 3; if (ow >= 56) ow -= 56;
    const size_t rowoff = (bbase + oh * 56 + ow) * 256;
    const float* xr = x + rowoff;
    float vals[16];
    float s = 0.f;
    #pragma unroll
    for (int ct = 0; ct < 16; ++ct) {
      const int o = ct * 16 + rq;
      const float v = pacc[ct][r] + bproj[o] + xr[o];
      vals[ct] = v; s += v;
    }
    #pragma unroll
    for (int off = 1; off < 16; off <<= 1) s += __shfl_xor(s, off);
    const float mean = s * (1.0f / 256.0f);
    float sq = 0.f;
    #pragma unroll
    for (int ct = 0; ct < 16; ++ct) { const float d_ = vals[ct] - mean; sq += d_ * d_; }
    #pragma unroll
    for (int off = 1; off < 16; off <<= 1) sq += __shfl_xor(sq, off);
    const float rstd = rsqrtf(sq * (1.0f / 256.0f) + 1e-5f);
    float* orow = out + rowoff;
    u16* xrow = xn2 + rowoff;
    #pragma unroll
    for (int ct = 0; ct < 16; ++ct) {
      const int o = ct * 16 + rq;
      orow[o] = vals[ct];
      xrow[o] = f2bf((vals[ct] - mean) * rstd * g2[o] + b2[o]);
    }
  }
}

// ---------------- MLP GEMMs (m97-style 128x128, BK=64, global_load_lds) ----------------
template<int K, int NOUT, bool GELU>
__global__ __launch_bounds__(256) void mlp_gemm(
    const u16* __restrict__ A, const u16* __restrict__ Bw,
    const float* __restrict__ bias, u16* __restrict__ obf, float* __restrict__ ofr)
{
  __shared__ __align__(16) u16 sA[128 * 64];
  __shared__ __align__(16) u16 sB[128 * 64];
  const int m0 = blockIdx.x * 128;
  const int nn0 = blockIdx.y * 128;
  const int tid = threadIdx.x;
  const int lane = tid & 63;
  const int wv = tid >> 6;
  const int wm = wv >> 1, wn = wv & 1;
  const int rq = lane & 15, kg = lane >> 4;
  f32x4 acc[4][4];
  #pragma unroll
  for (int i = 0; i < 4; ++i)
    #pragma unroll
    for (int j = 0; j < 4; ++j) acc[i][j] = f32x4{0,0,0,0};

  for (int kt = 0; kt < K / 64; ++kt) {
    if (kt) __syncthreads();
    #pragma unroll
    for (int i = 0; i < 4; ++i) {
      const int c = i * 256 + tid;
      gload16(A + (size_t)(m0 + (c >> 3)) * K + kt * 64 + (c & 7) * 8, sA + c * 8);
    }
    #pragma unroll
    for (int i = 0; i < 4; ++i) {
      const int c = i * 256 + tid;
      gload16(Bw + (size_t)(nn0 + (c >> 3)) * K + kt * 64 + (c & 7) * 8, sB + c * 8);
    }
    __syncthreads();
    #pragma unroll
    for (int k0 = 0; k0 < 2; ++k0) {
      short8 af[4], bf8[4];
      #pragma unroll
      for (int mt = 0; mt < 4; ++mt)
        af[mt] = *(const short8*)(sA + (wm * 64 + mt * 16 + rq) * 64 + k0 * 32 + kg * 8);
      #pragma unroll
      for (int nt = 0; nt < 4; ++nt)
        bf8[nt] = *(const short8*)(sB + (wn * 64 + nt * 16 + rq) * 64 + k0 * 32 + kg * 8);
      #pragma unroll
      for (int mt = 0; mt < 4; ++mt)
        #pragma unroll
        for (int nt = 0; nt < 4; ++nt)
          acc[mt][nt] = mfma16(af[mt], bf8[nt], acc[mt][nt]);
    }
  }
  #pragma unroll
  for (int mt = 0; mt < 4; ++mt) {
    #pragma unroll
    for (int nt = 0; nt < 4; ++nt) {
      const int col = nn0 + wn * 64 + nt * 16 + rq;
      const float bcol = bias[col];
      #pragma unroll
      for (int r = 0; r < 4; ++r) {
        const int row = m0 + wm * 64 + mt * 16 + kg * 4 + r;
        float v = acc[mt][nt][r] + bcol;
        if constexpr (GELU) {
          v = 0.5f * v * (1.0f + erff(v * 0.7071067811865476f));
          obf[(size_t)row * NOUT + col] = f2bf(v);
        } else {
          float* p = ofr + (size_t)row * NOUT + col;
          *p = v + *p;
        }
      }
    }
  }
}

extern "C" void kernel_launch(void* const* d_in, const int* in_sizes, int n_in,
                              void* d_out, int out_size, void* d_ws, size_t ws_size,
                              hipStream_t stream) {
  const float* x      = (const float*)d_in[0];
  const float* y      = (const float*)d_in[1];
  const float* g1     = (const float*)d_in[2];
  const float* b1     = (const float*)d_in[3];
  const float* rpb    = (const float*)d_in[4];
  const float* w_qkv  = (const float*)d_in[5];
  const float* b_qkv  = (const float*)d_in[6];
  const float* w_proj = (const float*)d_in[7];
  const float* b_proj = (const float*)d_in[8];
  const float* g2     = (const float*)d_in[9];
  const float* b2     = (const float*)d_in[10];
  const float* w_fc1  = (const float*)d_in[11];
  const float* b_fc1  = (const float*)d_in[12];
  const float* w_fc2  = (const float*)d_in[13];
  const float* b_fc2  = (const float*)d_in[14];
  float* out = (float*)d_out;

  u16* wsp = (u16*)d_ws;
  u16* wqkv_bf  = wsp;                       //  786432
  u16* wproj_bf = wsp + 786432;              //  131072
  u16* wfc1_bf  = wsp + 917504;              //  262144
  u16* wfc2_bf  = wsp + 1179648;             //  262144
  u16* xn2      = wsp + 1441792;             //  25690112
  u16* XYc      = wsp + 27131904;            //  12845056 (25088 x 512)
  u16* qkvc     = wsp + 39976960;            //  38535168 (24 planes x 25088 x 64)
  u16* hbuf     = XYc;                       //  overlay: 25690112 fits in XYc+qkvc (dead in MLP phase)

  convk<<<768, 256, 0, stream>>>(w_qkv,  wqkv_bf,  196608);
  convk<<<128, 256, 0, stream>>>(w_proj, wproj_bf, 32768);
  convk<<<256, 256, 0, stream>>>(w_fc1,  wfc1_bf,  65536);
  convk<<<256, 256, 0, stream>>>(w_fc2,  wfc2_bf,  65536);

  for (int c = 0; c < 4; ++c) {
    ln_gather<<<6272, 256, 0, stream>>>(x, y, g1, b1, XYc, c * CHUNK_ROWS);
    qkv_gemm<<<dim3(196, 12), 256, 0, stream>>>(XYc, wqkv_bf, b_qkv, qkvc);
    attn2<<<512, 256, 0, stream>>>(qkvc, rpb, wproj_bf, b_proj, x, g2, b2,
                                   out, xn2, c * 512);
  }

  for (int c = 0; c < 4; ++c) {
    mlp_gemm<256, 1024, true><<<dim3(196, 8), 256, 0, stream>>>(
        xn2 + (size_t)c * CHUNK_ROWS * 256, wfc1_bf, b_fc1, hbuf, nullptr);
    mlp_gemm<1024, 256, false><<<dim3(196, 2), 256, 0, stream>>>(
        hbuf, wfc2_bf, b_fc2, nullptr, out + (size_t)c * CHUNK_ROWS * 256);
  }
}

// Round 3
// 1218.038 us; speedup vs baseline: 2.0259x; 1.0753x over previous
//
#include <hip/hip_runtime.h>
#include <hip/hip_bf16.h>

#define DEVI __device__ __forceinline__

typedef __attribute__((ext_vector_type(8))) short short8;
typedef __attribute__((ext_vector_type(4))) float f32x4;
typedef unsigned int u32;
typedef unsigned short u16;

typedef __attribute__((address_space(1))) const u32 gu32_t;
typedef __attribute__((address_space(3))) u32 lu32_t;

DEVI u16 f2bf(float f) {
  u32 u = __builtin_bit_cast(u32, f);
  u32 r = (u + 0x7fffu + ((u >> 16) & 1u)) >> 16;
  return (u16)r;
}

DEVI f32x4 mfma16(short8 a, short8 b, f32x4 c) {
  return __builtin_amdgcn_mfma_f32_16x16x32_bf16(a, b, c, 0, 0, 0);
}

DEVI void gload16(const void* g, void* l) {
  __builtin_amdgcn_global_load_lds((gu32_t*)g, (lu32_t*)l, 16, 0, 0);
}

#define CHUNK_ROWS 25088   // 512 windows * 49 tokens
#define PLANE ((size_t)CHUNK_ROWS * 64)
#define KOFF  ((size_t)8 * PLANE)          // k planes base
#define VOFF  ((size_t)16 * PLANE)         // vT planes base
#define VT_PLANE ((size_t)512 * 4096)      // per-head vT: [wl][d:64][tok:64]

// ---------------- weight f32 -> bf16 ----------------
__global__ __launch_bounds__(256) void convk(const float* __restrict__ s, u16* __restrict__ d, int n4) {
  int i = blockIdx.x * 256 + threadIdx.x;
  if (i < n4) {
    const float4 v = ((const float4*)s)[i];
    ushort4 o;
    o.x = f2bf(v.x); o.y = f2bf(v.y); o.z = f2bf(v.z); o.w = f2bf(v.w);
    ((ushort4*)d)[i] = o;
  }
}

// ---------------- LN1 + shift + window gather -> XY bf16 [CHUNK_ROWS][512] ----------------
__global__ __launch_bounds__(256) void ln_gather(
    const float* __restrict__ x, const float* __restrict__ y,
    const float* __restrict__ g1, const float* __restrict__ b1,
    u16* __restrict__ XY, int rowbase)
{
  const int wv = threadIdx.x >> 6, lane = threadIdx.x & 63;
  const int rl = blockIdx.x * 4 + wv;
  const int row = rowbase + rl;
  const int w = row / 49, n = row - w * 49;
  const int b = w >> 6, win = w & 63, wh = win >> 3, ww = win & 7;
  const int r = n / 7, c = n - r * 7;
  int oh = wh * 7 + r + 3; if (oh >= 56) oh -= 56;
  int ow = ww * 7 + c + 3; if (ow >= 56) ow -= 56;
  const size_t po = ((size_t)b * 3136 + oh * 56 + ow) * 256;
  const float4 g1v = ((const float4*)g1)[lane];
  const float4 b1v = ((const float4*)b1)[lane];
  u16* orow = XY + (size_t)rl * 512;
  #pragma unroll
  for (int mod = 0; mod < 2; ++mod) {
    const float* src = (mod ? y : x) + po;
    const float4 v = ((const float4*)src)[lane];
    float s = v.x + v.y + v.z + v.w;
    #pragma unroll
    for (int off = 1; off < 64; off <<= 1) s += __shfl_xor(s, off);
    const float mean = s * (1.0f / 256.0f);
    const float d0 = v.x - mean, d1 = v.y - mean, d2 = v.z - mean, d3 = v.w - mean;
    float sq = d0 * d0 + d1 * d1 + d2 * d2 + d3 * d3;
    #pragma unroll
    for (int off = 1; off < 64; off <<= 1) sq += __shfl_xor(sq, off);
    const float rstd = rsqrtf(sq * (1.0f / 256.0f) + 1e-5f);
    ushort4 o;
    o.x = f2bf(d0 * rstd * g1v.x + b1v.x);
    o.y = f2bf(d1 * rstd * g1v.y + b1v.y);
    o.z = f2bf(d2 * rstd * g1v.z + b1v.z);
    o.w = f2bf(d3 * rstd * g1v.w + b1v.w);
    *(ushort4*)(orow + mod * 256 + lane * 4) = o;
  }
}

// ---------------- QKV GEMM: M=25088, N=1536, K=512 ----------------
// q,k -> [h][row][64]; v -> transposed per window [h][wl][d:64][tok:64]
__global__ __launch_bounds__(256) void qkv_gemm(
    const u16* __restrict__ A, const u16* __restrict__ Bw,
    const float* __restrict__ bias, u16* __restrict__ Qo)
{
  __shared__ __align__(16) u16 sA[128 * 64];
  __shared__ __align__(16) u16 sB[128 * 64];
  const int m0 = blockIdx.x * 128;
  const int nn0 = blockIdx.y * 128;
  const int tid = threadIdx.x;
  const int lane = tid & 63;
  const int wv = tid >> 6;
  const int wm = wv >> 1, wn = wv & 1;
  const int rq = lane & 15, kg = lane >> 4;
  f32x4 acc[4][4];
  #pragma unroll
  for (int i = 0; i < 4; ++i)
    #pragma unroll
    for (int j = 0; j < 4; ++j) acc[i][j] = f32x4{0,0,0,0};

  for (int kt = 0; kt < 8; ++kt) {
    if (kt) __syncthreads();
    #pragma unroll
    for (int i = 0; i < 4; ++i) {
      const int c = i * 256 + tid;
      gload16(A + (size_t)(m0 + (c >> 3)) * 512 + kt * 64 + (c & 7) * 8, sA + c * 8);
    }
    #pragma unroll
    for (int i = 0; i < 4; ++i) {
      const int c = i * 256 + tid;
      gload16(Bw + (size_t)(nn0 + (c >> 3)) * 512 + kt * 64 + (c & 7) * 8, sB + c * 8);
    }
    __syncthreads();
    #pragma unroll
    for (int k0 = 0; k0 < 2; ++k0) {
      short8 af[4], bf8[4];
      #pragma unroll
      for (int mt = 0; mt < 4; ++mt)
        af[mt] = *(const short8*)(sA + (wm * 64 + mt * 16 + rq) * 64 + k0 * 32 + kg * 8);
      #pragma unroll
      for (int nt = 0; nt < 4; ++nt)
        bf8[nt] = *(const short8*)(sB + (wn * 64 + nt * 16 + rq) * 64 + k0 * 32 + kg * 8);
      #pragma unroll
      for (int mt = 0; mt < 4; ++mt)
        #pragma unroll
        for (int nt = 0; nt < 4; ++nt)
          acc[mt][nt] = mfma16(af[mt], bf8[nt], acc[mt][nt]);
    }
  }
  #pragma unroll
  for (int mt = 0; mt < 4; ++mt) {
    #pragma unroll
    for (int nt = 0; nt < 4; ++nt) {
      const int col = nn0 + wn * 64 + nt * 16 + rq;
      const int t = col >> 9, rem = col & 511;
      const int h = rem >> 6, d = rem & 63;
      const float bc = bias[col];
      #pragma unroll
      for (int r = 0; r < 4; ++r) {
        const int row = m0 + wm * 64 + mt * 16 + kg * 4 + r;
        const float v = acc[mt][nt][r] + bc;
        if (t == 0) {
          Qo[(size_t)h * PLANE + (size_t)row * 64 + d] = f2bf(v * 0.17677669529663687f);
        } else if (t == 1) {
          Qo[KOFF + (size_t)h * PLANE + (size_t)row * 64 + d] = f2bf(v);
        } else {
          const u32 wl = (u32)row / 49u, n = (u32)row - wl * 49u;
          Qo[VOFF + (size_t)h * VT_PLANE + (size_t)wl * 4096 + d * 64 + n] = f2bf(v);
        }
      }
    }
  }
}

// ---------------- barrier-free attention: one wave per (window, head) ----------------
// grid = 1024 blocks x 256 thr (4 indep waves). Writes concat [row][512] bf16.
__global__ __launch_bounds__(256, 3) void attn3(
    const u16* __restrict__ qkv, const float* __restrict__ rpb,
    u16* __restrict__ concat, int wbase)
{
  __shared__ __align__(16) u16 sP[4][3136];   // per-wave P / out buffer (49 x 64, swizzled)
  __shared__ float sRpb[4][169];

  const int tid = threadIdx.x;
  const int wv = tid >> 6, lane = tid & 63;
  const int rq = lane & 15, kg = lane >> 4;
  const int gw = blockIdx.x * 4 + wv;
  const int wl = gw >> 3, h = gw & 7;
  const int w = wbase + wl;
  const int win = w & 63, wh = win >> 3, ww = win & 7;
  const bool edge = (wh == 7) || (ww == 7);
  u16* sPw = sP[wv];

  for (int e = lane; e < 169; e += 64) sRpb[wv][e] = rpb[e * 8 + h];

  const u16* qbase = qkv + (size_t)h * PLANE + (size_t)wl * 49 * 64;
  const u16* kbase = qkv + KOFF + (size_t)h * PLANE + (size_t)wl * 49 * 64;
  const u16* vbase = qkv + VOFF + (size_t)h * VT_PLANE + (size_t)wl * 4096;

  // ---- K fragments (all), then S with per-i Q loads ----
  short8 ak[4][2];
  #pragma unroll
  for (int j = 0; j < 4; ++j) {
    const int rr = (16 * j + rq) > 48 ? 48 : (16 * j + rq);
    ak[j][0] = *(const short8*)(kbase + rr * 64 + kg * 8);
    ak[j][1] = *(const short8*)(kbase + rr * 64 + 32 + kg * 8);
  }
  f32x4 sacc[4][4];
  #pragma unroll
  for (int i = 0; i < 4; ++i)
    #pragma unroll
    for (int j = 0; j < 4; ++j) sacc[i][j] = f32x4{0,0,0,0};
  #pragma unroll
  for (int i = 0; i < 4; ++i) {
    const int rr = (16 * i + rq) > 48 ? 48 : (16 * i + rq);
    const short8 a0 = *(const short8*)(qbase + rr * 64 + kg * 8);
    const short8 a1 = *(const short8*)(qbase + rr * 64 + 32 + kg * 8);
    #pragma unroll
    for (int j = 0; j < 4; ++j) {
      sacc[i][j] = mfma16(a0, ak[j][0], sacc[i][j]);
      sacc[i][j] = mfma16(a1, ak[j][1], sacc[i][j]);
    }
  }

  // ---- bias + mask + softmax; P -> sPw (swizzled) ----
  #pragma unroll
  for (int i = 0; i < 4; ++i) {
    #pragma unroll
    for (int r = 0; r < 4; ++r) {
      const int n = 16 * i + kg * 4 + r;
      const bool nv = n < 49;
      const int r1 = n / 7, c1 = n - r1 * 7;
      int reg1 = 0;
      if (edge && nv) {
        const int sh1 = wh * 7 + r1, sw1 = ww * 7 + c1;
        reg1 = (sh1 < 49 ? 0 : (sh1 < 53 ? 1 : 2)) * 3 + (sw1 < 49 ? 0 : (sw1 < 53 ? 1 : 2));
      }
      float pv[4];
      #pragma unroll
      for (int j = 0; j < 4; ++j) {
        const int m = 16 * j + rq;
        float sv = -1e30f;
        if (nv && m < 49) {
          const int r2 = m / 7, c2 = m - r2 * 7;
          const int rel = (r1 - r2 + 6) * 13 + (c1 - c2 + 6);
          float msk = 0.f;
          if (edge) {
            const int sh2 = wh * 7 + r2, sw2 = ww * 7 + c2;
            const int reg2 = (sh2 < 49 ? 0 : (sh2 < 53 ? 1 : 2)) * 3 + (sw2 < 49 ? 0 : (sw2 < 53 ? 1 : 2));
            msk = (reg1 == reg2) ? 0.f : -100.f;
          }
          sv = sacc[i][j][r] + sRpb[wv][rel] + msk;
        }
        pv[j] = sv;
      }
      float mx = fmaxf(fmaxf(pv[0], pv[1]), fmaxf(pv[2], pv[3]));
      #pragma unroll
      for (int off = 1; off < 16; off <<= 1) mx = fmaxf(mx, __shfl_xor(mx, off));
      float sm = 0.f;
      #pragma unroll
      for (int j = 0; j < 4; ++j) { const float e = __expf(pv[j] - mx); pv[j] = e; sm += e; }
      #pragma unroll
      for (int off = 1; off < 16; off <<= 1) sm += __shfl_xor(sm, off);
      const float inv = 1.0f / sm;
      if (nv) {
        #pragma unroll
        for (int j = 0; j < 4; ++j) {
          const int col = 16 * j + rq;
          sPw[n * 64 + (((col >> 3) ^ (n & 7)) << 3) + (col & 7)] = f2bf(pv[j] * inv);
        }
      }
    }
  }

  // ---- PV: A = P (LDS), B = vT (direct global, pad-masked) ----
  f32x4 oacc[4][4];
  #pragma unroll
  for (int i = 0; i < 4; ++i)
    #pragma unroll
    for (int j = 0; j < 4; ++j) oacc[i][j] = f32x4{0,0,0,0};
  #pragma unroll
  for (int m0v = 0; m0v < 2; ++m0v) {
    short8 av[4];
    #pragma unroll
    for (int ct = 0; ct < 4; ++ct) {
      short8 vvv = *(const short8*)(vbase + (ct * 16 + rq) * 64 + m0v * 32 + kg * 8);
      if (m0v == 1) {
        if (kg == 3) {
          #pragma unroll
          for (int e = 0; e < 8; ++e) vvv[e] = 0;        // tokens 56..63: pad
        } else if (kg == 2) {
          #pragma unroll
          for (int e = 1; e < 8; ++e) vvv[e] = 0;        // tokens 49..55: pad
        }
      }
      av[ct] = vvv;
    }
    #pragma unroll
    for (int i = 0; i < 4; ++i) {
      const int rr = (16 * i + rq) > 48 ? 48 : (16 * i + rq);
      const int ch = (m0v * 4 + kg) ^ (rr & 7);
      const short8 pa = *(const short8*)(sPw + rr * 64 + ch * 8);
      #pragma unroll
      for (int ct = 0; ct < 4; ++ct)
        oacc[i][ct] = mfma16(pa, av[ct], oacc[i][ct]);
    }
  }

  // ---- repack out_h through LDS (reuse sPw), coalesced b128 store ----
  #pragma unroll
  for (int i = 0; i < 4; ++i)
    #pragma unroll
    for (int ct = 0; ct < 4; ++ct)
      #pragma unroll
      for (int r = 0; r < 4; ++r) {
        const int n = 16 * i + kg * 4 + r;
        if (n < 49) {
          const int col = ct * 16 + rq;
          sPw[n * 64 + (((col >> 3) ^ (n & 7)) << 3) + (col & 7)] = f2bf(oacc[i][ct][r]);
        }
      }
  u16* crow = concat + (size_t)(wl * 49) * 512 + h * 64;
  #pragma unroll
  for (int it = 0; it < 7; ++it) {
    const int c = it * 64 + lane;
    if (c < 392) {
      const int m = c >> 3, s = c & 7;
      const short8 vvv = *(const short8*)(sPw + m * 64 + ((s ^ (m & 7)) << 3));
      *(short8*)(crow + (size_t)m * 512 + s * 8) = vvv;
    }
  }
}

// ---------------- proj GEMM: M=25088, N=256, K=512; + bias + residual, scatter to pixels ----------------
__global__ __launch_bounds__(256) void proj_gemm(
    const u16* __restrict__ A, const u16* __restrict__ Bw,
    const float* __restrict__ bias, const float* __restrict__ x,
    float* __restrict__ out, int rowbase)
{
  __shared__ __align__(16) u16 sA[128 * 64];
  __shared__ __align__(16) u16 sB[128 * 64];
  const int m0 = blockIdx.x * 128;
  const int nn0 = blockIdx.y * 128;
  const int tid = threadIdx.x;
  const int lane = tid & 63;
  const int wv = tid >> 6;
  const int wm = wv >> 1, wn = wv & 1;
  const int rq = lane & 15, kg = lane >> 4;
  f32x4 acc[4][4];
  #pragma unroll
  for (int i = 0; i < 4; ++i)
    #pragma unroll
    for (int j = 0; j < 4; ++j) acc[i][j] = f32x4{0,0,0,0};

  for (int kt = 0; kt < 8; ++kt) {
    if (kt) __syncthreads();
    #pragma unroll
    for (int i = 0; i < 4; ++i) {
      const int c = i * 256 + tid;
      gload16(A + (size_t)(m0 + (c >> 3)) * 512 + kt * 64 + (c & 7) * 8, sA + c * 8);
    }
    #pragma unroll
    for (int i = 0; i < 4; ++i) {
      const int c = i * 256 + tid;
      gload16(Bw + (size_t)(nn0 + (c >> 3)) * 512 + kt * 64 + (c & 7) * 8, sB + c * 8);
    }
    __syncthreads();
    #pragma unroll
    for (int k0 = 0; k0 < 2; ++k0) {
      short8 af[4], bf8[4];
      #pragma unroll
      for (int mt = 0; mt < 4; ++mt)
        af[mt] = *(const short8*)(sA + (wm * 64 + mt * 16 + rq) * 64 + k0 * 32 + kg * 8);
      #pragma unroll
      for (int nt = 0; nt < 4; ++nt)
        bf8[nt] = *(const short8*)(sB + (wn * 64 + nt * 16 + rq) * 64 + k0 * 32 + kg * 8);
      #pragma unroll
      for (int mt = 0; mt < 4; ++mt)
        #pragma unroll
        for (int nt = 0; nt < 4; ++nt)
          acc[mt][nt] = mfma16(af[mt], bf8[nt], acc[mt][nt]);
    }
  }
  #pragma unroll
  for (int mt = 0; mt < 4; ++mt) {
    #pragma unroll
    for (int r = 0; r < 4; ++r) {
      const int row = m0 + wm * 64 + mt * 16 + kg * 4 + r;
      const u32 g = (u32)(rowbase + row);
      const u32 w = g / 49u; const u32 n = g - w * 49u;
      const int b = w >> 6, win = w & 63, wh = win >> 3, ww = win & 7;
      const u32 rr = n / 7u; const u32 cc = n - rr * 7u;
      int oh = wh * 7 + (int)rr + 3; if (oh >= 56) oh -= 56;
      int ow = ww * 7 + (int)cc + 3; if (ow >= 56) ow -= 56;
      const size_t po = ((size_t)b * 3136 + oh * 56 + ow) * 256;
      #pragma unroll
      for (int nt = 0; nt < 4; ++nt) {
        const int col = nn0 + wn * 64 + nt * 16 + rq;
        out[po + col] = acc[mt][nt][r] + bias[col] + x[po + col];
      }
    }
  }
}

// ---------------- LN2 over full x2 (pixel-major) -> xn2 bf16 ----------------
__global__ __launch_bounds__(256) void ln2k(
    const float* __restrict__ out, const float* __restrict__ g2,
    const float* __restrict__ b2, u16* __restrict__ xn2)
{
  const int wv = threadIdx.x >> 6, lane = threadIdx.x & 63;
  const size_t row = blockIdx.x * 4 + wv;
  const float4 v = ((const float4*)(out + row * 256))[lane];
  float s = v.x + v.y + v.z + v.w;
  #pragma unroll
  for (int off = 1; off < 64; off <<= 1) s += __shfl_xor(s, off);
  const float mean = s * (1.0f / 256.0f);
  const float d0 = v.x - mean, d1 = v.y - mean, d2 = v.z - mean, d3 = v.w - mean;
  float sq = d0 * d0 + d1 * d1 + d2 * d2 + d3 * d3;
  #pragma unroll
  for (int off = 1; off < 64; off <<= 1) sq += __shfl_xor(sq, off);
  const float rstd = rsqrtf(sq * (1.0f / 256.0f) + 1e-5f);
  const float4 g2v = ((const float4*)g2)[lane];
  const float4 b2v = ((const float4*)b2)[lane];
  ushort4 o;
  o.x = f2bf(d0 * rstd * g2v.x + b2v.x);
  o.y = f2bf(d1 * rstd * g2v.y + b2v.y);
  o.z = f2bf(d2 * rstd * g2v.z + b2v.z);
  o.w = f2bf(d3 * rstd * g2v.w + b2v.w);
  ((ushort4*)(xn2 + row * 256))[lane] = o;
}

// ---------------- MLP GEMMs ----------------
template<int K, int NOUT, bool GELU>
__global__ __launch_bounds__(256) void mlp_gemm(
    const u16* __restrict__ A, const u16* __restrict__ Bw,
    const float* __restrict__ bias, u16* __restrict__ obf, float* __restrict__ ofr)
{
  __shared__ __align__(16) u16 sA[128 * 64];
  __shared__ __align__(16) u16 sB[128 * 64];
  const int m0 = blockIdx.x * 128;
  const int nn0 = blockIdx.y * 128;
  const int tid = threadIdx.x;
  const int lane = tid & 63;
  const int wv = tid >> 6;
  const int wm = wv >> 1, wn = wv & 1;
  const int rq = lane & 15, kg = lane >> 4;
  f32x4 acc[4][4];
  #pragma unroll
  for (int i = 0; i < 4; ++i)
    #pragma unroll
    for (int j = 0; j < 4; ++j) acc[i][j] = f32x4{0,0,0,0};

  for (int kt = 0; kt < K / 64; ++kt) {
    if (kt) __syncthreads();
    #pragma unroll
    for (int i = 0; i < 4; ++i) {
      const int c = i * 256 + tid;
      gload16(A + (size_t)(m0 + (c >> 3)) * K + kt * 64 + (c & 7) * 8, sA + c * 8);
    }
    #pragma unroll
    for (int i = 0; i < 4; ++i) {
      const int c = i * 256 + tid;
      gload16(Bw + (size_t)(nn0 + (c >> 3)) * K + kt * 64 + (c & 7) * 8, sB + c * 8);
    }
    __syncthreads();
    #pragma unroll
    for (int k0 = 0; k0 < 2; ++k0) {
      short8 af[4], bf8[4];
      #pragma unroll
      for (int mt = 0; mt < 4; ++mt)
        af[mt] = *(const short8*)(sA + (wm * 64 + mt * 16 + rq) * 64 + k0 * 32 + kg * 8);
      #pragma unroll
      for (int nt = 0; nt < 4; ++nt)
        bf8[nt] = *(const short8*)(sB + (wn * 64 + nt * 16 + rq) * 64 + k0 * 32 + kg * 8);
      #pragma unroll
      for (int mt = 0; mt < 4; ++mt)
        #pragma unroll
        for (int nt = 0; nt < 4; ++nt)
          acc[mt][nt] = mfma16(af[mt], bf8[nt], acc[mt][nt]);
    }
  }
  #pragma unroll
  for (int mt = 0; mt < 4; ++mt) {
    #pragma unroll
    for (int nt = 0; nt < 4; ++nt) {
      const int col = nn0 + wn * 64 + nt * 16 + rq;
      const float bcol = bias[col];
      #pragma unroll
      for (int r = 0; r < 4; ++r) {
        const int row = m0 + wm * 64 + mt * 16 + kg * 4 + r;
        float v = acc[mt][nt][r] + bcol;
        if constexpr (GELU) {
          v = 0.5f * v * (1.0f + erff(v * 0.7071067811865476f));
          obf[(size_t)row * NOUT + col] = f2bf(v);
        } else {
          float* p = ofr + (size_t)row * NOUT + col;
          *p = v + *p;
        }
      }
    }
  }
}

extern "C" void kernel_launch(void* const* d_in, const int* in_sizes, int n_in,
                              void* d_out, int out_size, void* d_ws, size_t ws_size,
                              hipStream_t stream) {
  const float* x      = (const float*)d_in[0];
  const float* y      = (const float*)d_in[1];
  const float* g1     = (const float*)d_in[2];
  const float* b1     = (const float*)d_in[3];
  const float* rpb    = (const float*)d_in[4];
  const float* w_qkv  = (const float*)d_in[5];
  const float* b_qkv  = (const float*)d_in[6];
  const float* w_proj = (const float*)d_in[7];
  const float* b_proj = (const float*)d_in[8];
  const float* g2     = (const float*)d_in[9];
  const float* b2     = (const float*)d_in[10];
  const float* w_fc1  = (const float*)d_in[11];
  const float* b_fc1  = (const float*)d_in[12];
  const float* w_fc2  = (const float*)d_in[13];
  const float* b_fc2  = (const float*)d_in[14];
  float* out = (float*)d_out;

  u16* wsp = (u16*)d_ws;
  u16* wqkv_bf  = wsp;                       //  786432
  u16* wproj_bf = wsp + 786432;              //  131072
  u16* wfc1_bf  = wsp + 917504;              //  262144
  u16* wfc2_bf  = wsp + 1179648;             //  262144
  u16* xn2      = wsp + 1441792;             //  25690112
  u16* XYc      = wsp + 27131904;            //  12845056 (25088 x 512) XY, then concat
  u16* qkvc     = wsp + 39976960;            //  42467328 (q,k 8 planes each + vT 8 planes)
  u16* hbuf     = XYc;                       //  overlay (dead in MLP phase)

  convk<<<768, 256, 0, stream>>>(w_qkv,  wqkv_bf,  196608);
  convk<<<128, 256, 0, stream>>>(w_proj, wproj_bf, 32768);
  convk<<<256, 256, 0, stream>>>(w_fc1,  wfc1_bf,  65536);
  convk<<<256, 256, 0, stream>>>(w_fc2,  wfc2_bf,  65536);

  for (int c = 0; c < 4; ++c) {
    ln_gather<<<6272, 256, 0, stream>>>(x, y, g1, b1, XYc, c * CHUNK_ROWS);
    qkv_gemm<<<dim3(196, 12), 256, 0, stream>>>(XYc, wqkv_bf, b_qkv, qkvc);
    attn3<<<1024, 256, 0, stream>>>(qkvc, rpb, XYc, c * 512);
    proj_gemm<<<dim3(196, 2), 256, 0, stream>>>(XYc, wproj_bf, b_proj, x, out, c * CHUNK_ROWS);
  }

  ln2k<<<25088, 256, 0, stream>>>(out, g2, b2, xn2);

  for (int c = 0; c < 4; ++c) {
    mlp_gemm<256, 1024, true><<<dim3(196, 8), 256, 0, stream>>>(
        xn2 + (size_t)c * CHUNK_ROWS * 256, wfc1_bf, b_fc1, hbuf, nullptr);
    mlp_gemm<1024, 256, false><<<dim3(196, 2), 256, 0, stream>>>(
        hbuf, wfc2_bf, b_fc2, nullptr, out + (size_t)c * CHUNK_ROWS * 256);
  }
}

// Round 4
// 1039.011 us; speedup vs baseline: 2.3749x; 1.1723x over previous
//
#include <hip/hip_runtime.h>
#include <hip/hip_bf16.h>

#define DEVI __device__ __forceinline__

typedef __attribute__((ext_vector_type(8))) short short8;
typedef __attribute__((ext_vector_type(4))) float f32x4;
typedef unsigned int u32;
typedef unsigned short u16;

typedef __attribute__((address_space(1))) const u32 gu32_t;
typedef __attribute__((address_space(3))) u32 lu32_t;

DEVI u16 f2bf(float f) {
  u32 u = __builtin_bit_cast(u32, f);
  u32 r = (u + 0x7fffu + ((u >> 16) & 1u)) >> 16;
  return (u16)r;
}

DEVI f32x4 mfma16(short8 a, short8 b, f32x4 c) {
  return __builtin_amdgcn_mfma_f32_16x16x32_bf16(a, b, c, 0, 0, 0);
}

DEVI void gload16(const void* g, void* l) {
  __builtin_amdgcn_global_load_lds((gu32_t*)g, (lu32_t*)l, 16, 0, 0);
}

#define CHUNK_ROWS 25088   // 512 windows * 49 tokens
#define PLANE ((size_t)CHUNK_ROWS * 64)
#define KOFF  ((size_t)8 * PLANE)          // k planes base
#define VOFF  ((size_t)16 * PLANE)         // v planes base (linear, like q/k)

// ---------------- weight f32 -> bf16 ----------------
__global__ __launch_bounds__(256) void convk(const float* __restrict__ s, u16* __restrict__ d, int n4) {
  int i = blockIdx.x * 256 + threadIdx.x;
  if (i < n4) {
    const float4 v = ((const float4*)s)[i];
    ushort4 o;
    o.x = f2bf(v.x); o.y = f2bf(v.y); o.z = f2bf(v.z); o.w = f2bf(v.w);
    ((ushort4*)d)[i] = o;
  }
}

// ---------------- LN1 + shift + window gather -> XY bf16 [CHUNK_ROWS][512] ----------------
__global__ __launch_bounds__(256) void ln_gather(
    const float* __restrict__ x, const float* __restrict__ y,
    const float* __restrict__ g1, const float* __restrict__ b1,
    u16* __restrict__ XY, int rowbase)
{
  const int wv = threadIdx.x >> 6, lane = threadIdx.x & 63;
  const int rl = blockIdx.x * 4 + wv;
  const int row = rowbase + rl;
  const int w = row / 49, n = row - w * 49;
  const int b = w >> 6, win = w & 63, wh = win >> 3, ww = win & 7;
  const int r = n / 7, c = n - r * 7;
  int oh = wh * 7 + r + 3; if (oh >= 56) oh -= 56;
  int ow = ww * 7 + c + 3; if (ow >= 56) ow -= 56;
  const size_t po = ((size_t)b * 3136 + oh * 56 + ow) * 256;
  const float4 g1v = ((const float4*)g1)[lane];
  const float4 b1v = ((const float4*)b1)[lane];
  u16* orow = XY + (size_t)rl * 512;
  #pragma unroll
  for (int mod = 0; mod < 2; ++mod) {
    const float* src = (mod ? y : x) + po;
    const float4 v = ((const float4*)src)[lane];
    float s = v.x + v.y + v.z + v.w;
    #pragma unroll
    for (int off = 1; off < 64; off <<= 1) s += __shfl_xor(s, off);
    const float mean = s * (1.0f / 256.0f);
    const float d0 = v.x - mean, d1 = v.y - mean, d2 = v.z - mean, d3 = v.w - mean;
    float sq = d0 * d0 + d1 * d1 + d2 * d2 + d3 * d3;
    #pragma unroll
    for (int off = 1; off < 64; off <<= 1) sq += __shfl_xor(sq, off);
    const float rstd = rsqrtf(sq * (1.0f / 256.0f) + 1e-5f);
    ushort4 o;
    o.x = f2bf(d0 * rstd * g1v.x + b1v.x);
    o.y = f2bf(d1 * rstd * g1v.y + b1v.y);
    o.z = f2bf(d2 * rstd * g1v.z + b1v.z);
    o.w = f2bf(d3 * rstd * g1v.w + b1v.w);
    *(ushort4*)(orow + mod * 256 + lane * 4) = o;
  }
}

// ---------------- QKV GEMM: M=25088, N=1536, K=512 -> q,k,v linear [t][h][row][64] ----------------
// grid = (12 n-tiles, 196 m-tiles): consecutive blocks share the A panel; B stays L2-resident.
__global__ __launch_bounds__(256) void qkv_gemm(
    const u16* __restrict__ A, const u16* __restrict__ Bw,
    const float* __restrict__ bias, u16* __restrict__ Qo)
{
  __shared__ __align__(16) u16 sA[128 * 64];
  __shared__ __align__(16) u16 sB[128 * 64];
  const int m0 = blockIdx.y * 128;
  const int nn0 = blockIdx.x * 128;
  const int tid = threadIdx.x;
  const int lane = tid & 63;
  const int wv = tid >> 6;
  const int wm = wv >> 1, wn = wv & 1;
  const int rq = lane & 15, kg = lane >> 4;
  f32x4 acc[4][4];
  #pragma unroll
  for (int i = 0; i < 4; ++i)
    #pragma unroll
    for (int j = 0; j < 4; ++j) acc[i][j] = f32x4{0,0,0,0};

  for (int kt = 0; kt < 8; ++kt) {
    if (kt) __syncthreads();
    #pragma unroll
    for (int i = 0; i < 4; ++i) {
      const int c = i * 256 + tid;
      gload16(A + (size_t)(m0 + (c >> 3)) * 512 + kt * 64 + (c & 7) * 8, sA + c * 8);
    }
    #pragma unroll
    for (int i = 0; i < 4; ++i) {
      const int c = i * 256 + tid;
      gload16(Bw + (size_t)(nn0 + (c >> 3)) * 512 + kt * 64 + (c & 7) * 8, sB + c * 8);
    }
    __syncthreads();
    #pragma unroll
    for (int k0 = 0; k0 < 2; ++k0) {
      short8 af[4], bf8[4];
      #pragma unroll
      for (int mt = 0; mt < 4; ++mt)
        af[mt] = *(const short8*)(sA + (wm * 64 + mt * 16 + rq) * 64 + k0 * 32 + kg * 8);
      #pragma unroll
      for (int nt = 0; nt < 4; ++nt)
        bf8[nt] = *(const short8*)(sB + (wn * 64 + nt * 16 + rq) * 64 + k0 * 32 + kg * 8);
      #pragma unroll
      for (int mt = 0; mt < 4; ++mt)
        #pragma unroll
        for (int nt = 0; nt < 4; ++nt)
          acc[mt][nt] = mfma16(af[mt], bf8[nt], acc[mt][nt]);
    }
  }
  #pragma unroll
  for (int mt = 0; mt < 4; ++mt) {
    #pragma unroll
    for (int nt = 0; nt < 4; ++nt) {
      const int col = nn0 + wn * 64 + nt * 16 + rq;
      const int t = col >> 9, rem = col & 511;
      const int h = rem >> 6, d = rem & 63;
      const float bc = bias[col];
      const float sc = (t == 0) ? 0.17677669529663687f : 1.0f;
      u16* bp = Qo + (size_t)(t * 8 + h) * PLANE + d;
      #pragma unroll
      for (int r = 0; r < 4; ++r) {
        const int row = m0 + wm * 64 + mt * 16 + kg * 4 + r;
        bp[(size_t)row * 64] = f2bf((acc[mt][nt][r] + bc) * sc);
      }
    }
  }
}

// ---------------- barrier-free attention: one wave per (window, head) ----------------
// grid = 1024 blocks x 256 thr (4 indep waves). Writes concat [row][512] bf16.
__global__ __launch_bounds__(256, 3) void attn3(
    const u16* __restrict__ qkv, const float* __restrict__ rpb,
    u16* __restrict__ concat, int wbase)
{
  __shared__ __align__(16) u16 sP[4][3136];   // per-wave P / out buffer (49 x 64, swizzled)
  __shared__ float sRpb[4][169];

  const int tid = threadIdx.x;
  const int wv = tid >> 6, lane = tid & 63;
  const int rq = lane & 15, kg = lane >> 4;
  const int gw = blockIdx.x * 4 + wv;
  const int wl = gw >> 3, h = gw & 7;
  const int w = wbase + wl;
  const int win = w & 63, wh = win >> 3, ww = win & 7;
  const bool edge = (wh == 7) || (ww == 7);
  u16* sPw = sP[wv];

  for (int e = lane; e < 169; e += 64) sRpb[wv][e] = rpb[e * 8 + h];

  const u16* qbase = qkv + (size_t)h * PLANE + (size_t)wl * 49 * 64;
  const u16* kbase = qkv + KOFF + (size_t)h * PLANE + (size_t)wl * 49 * 64;
  const u16* vbase = qkv + VOFF + (size_t)h * PLANE + (size_t)wl * 49 * 64;

  // ---- K fragments (all), then S with per-i Q loads ----
  short8 ak[4][2];
  #pragma unroll
  for (int j = 0; j < 4; ++j) {
    const int rr = (16 * j + rq) > 48 ? 48 : (16 * j + rq);
    ak[j][0] = *(const short8*)(kbase + rr * 64 + kg * 8);
    ak[j][1] = *(const short8*)(kbase + rr * 64 + 32 + kg * 8);
  }
  f32x4 sacc[4][4];
  #pragma unroll
  for (int i = 0; i < 4; ++i)
    #pragma unroll
    for (int j = 0; j < 4; ++j) sacc[i][j] = f32x4{0,0,0,0};
  #pragma unroll
  for (int i = 0; i < 4; ++i) {
    const int rr = (16 * i + rq) > 48 ? 48 : (16 * i + rq);
    const short8 a0 = *(const short8*)(qbase + rr * 64 + kg * 8);
    const short8 a1 = *(const short8*)(qbase + rr * 64 + 32 + kg * 8);
    #pragma unroll
    for (int j = 0; j < 4; ++j) {
      sacc[i][j] = mfma16(a0, ak[j][0], sacc[i][j]);
      sacc[i][j] = mfma16(a1, ak[j][1], sacc[i][j]);
    }
  }

  // ---- bias + mask + softmax; P -> sPw (swizzled) ----
  #pragma unroll
  for (int i = 0; i < 4; ++i) {
    #pragma unroll
    for (int r = 0; r < 4; ++r) {
      const int n = 16 * i + kg * 4 + r;
      const bool nv = n < 49;
      const int r1 = n / 7, c1 = n - r1 * 7;
      int reg1 = 0;
      if (edge && nv) {
        const int sh1 = wh * 7 + r1, sw1 = ww * 7 + c1;
        reg1 = (sh1 < 49 ? 0 : (sh1 < 53 ? 1 : 2)) * 3 + (sw1 < 49 ? 0 : (sw1 < 53 ? 1 : 2));
      }
      float pv[4];
      #pragma unroll
      for (int j = 0; j < 4; ++j) {
        const int m = 16 * j + rq;
        float sv = -1e30f;
        if (nv && m < 49) {
          const int r2 = m / 7, c2 = m - r2 * 7;
          const int rel = (r1 - r2 + 6) * 13 + (c1 - c2 + 6);
          float msk = 0.f;
          if (edge) {
            const int sh2 = wh * 7 + r2, sw2 = ww * 7 + c2;
            const int reg2 = (sh2 < 49 ? 0 : (sh2 < 53 ? 1 : 2)) * 3 + (sw2 < 49 ? 0 : (sw2 < 53 ? 1 : 2));
            msk = (reg1 == reg2) ? 0.f : -100.f;
          }
          sv = sacc[i][j][r] + sRpb[wv][rel] + msk;
        }
        pv[j] = sv;
      }
      float mx = fmaxf(fmaxf(pv[0], pv[1]), fmaxf(pv[2], pv[3]));
      #pragma unroll
      for (int off = 1; off < 16; off <<= 1) mx = fmaxf(mx, __shfl_xor(mx, off));
      float sm = 0.f;
      #pragma unroll
      for (int j = 0; j < 4; ++j) { const float e = __expf(pv[j] - mx); pv[j] = e; sm += e; }
      #pragma unroll
      for (int off = 1; off < 16; off <<= 1) sm += __shfl_xor(sm, off);
      const float inv = 1.0f / sm;
      if (nv) {
        #pragma unroll
        for (int j = 0; j < 4; ++j) {
          const int col = 16 * j + rq;
          sPw[n * 64 + (((col >> 3) ^ (n & 7)) << 3) + (col & 7)] = f2bf(pv[j] * inv);
        }
      }
    }
  }

  // ---- PV: A = P (LDS), B built from v-linear (scalar loads, pad toks zeroed) ----
  f32x4 oacc[4][4];
  #pragma unroll
  for (int i = 0; i < 4; ++i)
    #pragma unroll
    for (int j = 0; j < 4; ++j) oacc[i][j] = f32x4{0,0,0,0};
  #pragma unroll
  for (int m0v = 0; m0v < 2; ++m0v) {
    const int tok0 = m0v * 32 + kg * 8;
    short8 av[4];
    #pragma unroll
    for (int ct = 0; ct < 4; ++ct) {
      const int d_ = ct * 16 + rq;
      short8 vvv;
      #pragma unroll
      for (int j = 0; j < 8; ++j) {
        const int tk = tok0 + j;
        const u16 lv = vbase[(size_t)tk * 64 + d_];
        vvv[j] = (tk < 49) ? (short)lv : (short)0;
      }
      av[ct] = vvv;
    }
    #pragma unroll
    for (int i = 0; i < 4; ++i) {
      const int rr = (16 * i + rq) > 48 ? 48 : (16 * i + rq);
      const int ch = (m0v * 4 + kg) ^ (rr & 7);
      const short8 pa = *(const short8*)(sPw + rr * 64 + ch * 8);
      #pragma unroll
      for (int ct = 0; ct < 4; ++ct)
        oacc[i][ct] = mfma16(pa, av[ct], oacc[i][ct]);
    }
  }

  // ---- repack out_h through LDS (reuse sPw), coalesced b128 store ----
  __builtin_amdgcn_s_waitcnt(0);  // wave-local LDS reuse: P reads done (single wave)
  #pragma unroll
  for (int i = 0; i < 4; ++i)
    #pragma unroll
    for (int ct = 0; ct < 4; ++ct)
      #pragma unroll
      for (int r = 0; r < 4; ++r) {
        const int n = 16 * i + kg * 4 + r;
        if (n < 49) {
          const int col = ct * 16 + rq;
          sPw[n * 64 + (((col >> 3) ^ (n & 7)) << 3) + (col & 7)] = f2bf(oacc[i][ct][r]);
        }
      }
  u16* crow = concat + (size_t)(wl * 49) * 512 + h * 64;
  #pragma unroll
  for (int it = 0; it < 7; ++it) {
    const int c = it * 64 + lane;
    if (c < 392) {
      const int m = c >> 3, s = c & 7;
      const short8 vvv = *(const short8*)(sPw + m * 64 + ((s ^ (m & 7)) << 3));
      *(short8*)(crow + (size_t)m * 512 + s * 8) = vvv;
    }
  }
}

// ---------------- proj GEMM: M=25088, N=256, K=512; + bias + residual, scatter to pixels ----------------
__global__ __launch_bounds__(256) void proj_gemm(
    const u16* __restrict__ A, const u16* __restrict__ Bw,
    const float* __restrict__ bias, const float* __restrict__ x,
    float* __restrict__ out, int rowbase)
{
  __shared__ __align__(16) u16 sA[128 * 64];
  __shared__ __align__(16) u16 sB[128 * 64];
  const int m0 = blockIdx.y * 128;
  const int nn0 = blockIdx.x * 128;
  const int tid = threadIdx.x;
  const int lane = tid & 63;
  const int wv = tid >> 6;
  const int wm = wv >> 1, wn = wv & 1;
  const int rq = lane & 15, kg = lane >> 4;
  f32x4 acc[4][4];
  #pragma unroll
  for (int i = 0; i < 4; ++i)
    #pragma unroll
    for (int j = 0; j < 4; ++j) acc[i][j] = f32x4{0,0,0,0};

  for (int kt = 0; kt < 8; ++kt) {
    if (kt) __syncthreads();
    #pragma unroll
    for (int i = 0; i < 4; ++i) {
      const int c = i * 256 + tid;
      gload16(A + (size_t)(m0 + (c >> 3)) * 512 + kt * 64 + (c & 7) * 8, sA + c * 8);
    }
    #pragma unroll
    for (int i = 0; i < 4; ++i) {
      const int c = i * 256 + tid;
      gload16(Bw + (size_t)(nn0 + (c >> 3)) * 512 + kt * 64 + (c & 7) * 8, sB + c * 8);
    }
    __syncthreads();
    #pragma unroll
    for (int k0 = 0; k0 < 2; ++k0) {
      short8 af[4], bf8[4];
      #pragma unroll
      for (int mt = 0; mt < 4; ++mt)
        af[mt] = *(const short8*)(sA + (wm * 64 + mt * 16 + rq) * 64 + k0 * 32 + kg * 8);
      #pragma unroll
      for (int nt = 0; nt < 4; ++nt)
        bf8[nt] = *(const short8*)(sB + (wn * 64 + nt * 16 + rq) * 64 + k0 * 32 + kg * 8);
      #pragma unroll
      for (int mt = 0; mt < 4; ++mt)
        #pragma unroll
        for (int nt = 0; nt < 4; ++nt)
          acc[mt][nt] = mfma16(af[mt], bf8[nt], acc[mt][nt]);
    }
  }
  #pragma unroll
  for (int mt = 0; mt < 4; ++mt) {
    #pragma unroll
    for (int r = 0; r < 4; ++r) {
      const int row = m0 + wm * 64 + mt * 16 + kg * 4 + r;
      const u32 g = (u32)(rowbase + row);
      const u32 w = g / 49u; const u32 n = g - w * 49u;
      const int b = w >> 6, win = w & 63, wh = win >> 3, ww = win & 7;
      const u32 rr = n / 7u; const u32 cc = n - rr * 7u;
      int oh = wh * 7 + (int)rr + 3; if (oh >= 56) oh -= 56;
      int ow = ww * 7 + (int)cc + 3; if (ow >= 56) ow -= 56;
      const size_t po = ((size_t)b * 3136 + oh * 56 + ow) * 256;
      #pragma unroll
      for (int nt = 0; nt < 4; ++nt) {
        const int col = nn0 + wn * 64 + nt * 16 + rq;
        out[po + col] = acc[mt][nt][r] + bias[col] + x[po + col];
      }
    }
  }
}

// ---------------- LN2 over full x2 (pixel-major) -> xn2 bf16 ----------------
__global__ __launch_bounds__(256) void ln2k(
    const float* __restrict__ out, const float* __restrict__ g2,
    const float* __restrict__ b2, u16* __restrict__ xn2)
{
  const int wv = threadIdx.x >> 6, lane = threadIdx.x & 63;
  const size_t row = blockIdx.x * 4 + wv;
  const float4 v = ((const float4*)(out + row * 256))[lane];
  float s = v.x + v.y + v.z + v.w;
  #pragma unroll
  for (int off = 1; off < 64; off <<= 1) s += __shfl_xor(s, off);
  const float mean = s * (1.0f / 256.0f);
  const float d0 = v.x - mean, d1 = v.y - mean, d2 = v.z - mean, d3 = v.w - mean;
  float sq = d0 * d0 + d1 * d1 + d2 * d2 + d3 * d3;
  #pragma unroll
  for (int off = 1; off < 64; off <<= 1) sq += __shfl_xor(sq, off);
  const float rstd = rsqrtf(sq * (1.0f / 256.0f) + 1e-5f);
  const float4 g2v = ((const float4*)g2)[lane];
  const float4 b2v = ((const float4*)b2)[lane];
  ushort4 o;
  o.x = f2bf(d0 * rstd * g2v.x + b2v.x);
  o.y = f2bf(d1 * rstd * g2v.y + b2v.y);
  o.z = f2bf(d2 * rstd * g2v.z + b2v.z);
  o.w = f2bf(d3 * rstd * g2v.w + b2v.w);
  ((ushort4*)(xn2 + row * 256))[lane] = o;
}

// ---------------- MLP GEMMs ----------------
template<int K, int NOUT, bool GELU>
__global__ __launch_bounds__(256) void mlp_gemm(
    const u16* __restrict__ A, const u16* __restrict__ Bw,
    const float* __restrict__ bias, u16* __restrict__ obf, float* __restrict__ ofr)
{
  __shared__ __align__(16) u16 sA[128 * 64];
  __shared__ __align__(16) u16 sB[128 * 64];
  const int m0 = blockIdx.y * 128;
  const int nn0 = blockIdx.x * 128;
  const int tid = threadIdx.x;
  const int lane = tid & 63;
  const int wv = tid >> 6;
  const int wm = wv >> 1, wn = wv & 1;
  const int rq = lane & 15, kg = lane >> 4;
  f32x4 acc[4][4];
  #pragma unroll
  for (int i = 0; i < 4; ++i)
    #pragma unroll
    for (int j = 0; j < 4; ++j) acc[i][j] = f32x4{0,0,0,0};

  for (int kt = 0; kt < K / 64; ++kt) {
    if (kt) __syncthreads();
    #pragma unroll
    for (int i = 0; i < 4; ++i) {
      const int c = i * 256 + tid;
      gload16(A + (size_t)(m0 + (c >> 3)) * K + kt * 64 + (c & 7) * 8, sA + c * 8);
    }
    #pragma unroll
    for (int i = 0; i < 4; ++i) {
      const int c = i * 256 + tid;
      gload16(Bw + (size_t)(nn0 + (c >> 3)) * K + kt * 64 + (c & 7) * 8, sB + c * 8);
    }
    __syncthreads();
    #pragma unroll
    for (int k0 = 0; k0 < 2; ++k0) {
      short8 af[4], bf8[4];
      #pragma unroll
      for (int mt = 0; mt < 4; ++mt)
        af[mt] = *(const short8*)(sA + (wm * 64 + mt * 16 + rq) * 64 + k0 * 32 + kg * 8);
      #pragma unroll
      for (int nt = 0; nt < 4; ++nt)
        bf8[nt] = *(const short8*)(sB + (wn * 64 + nt * 16 + rq) * 64 + k0 * 32 + kg * 8);
      #pragma unroll
      for (int mt = 0; mt < 4; ++mt)
        #pragma unroll
        for (int nt = 0; nt < 4; ++nt)
          acc[mt][nt] = mfma16(af[mt], bf8[nt], acc[mt][nt]);
    }
  }
  #pragma unroll
  for (int mt = 0; mt < 4; ++mt) {
    #pragma unroll
    for (int nt = 0; nt < 4; ++nt) {
      const int col = nn0 + wn * 64 + nt * 16 + rq;
      const float bcol = bias[col];
      #pragma unroll
      for (int r = 0; r < 4; ++r) {
        const int row = m0 + wm * 64 + mt * 16 + kg * 4 + r;
        float v = acc[mt][nt][r] + bcol;
        if constexpr (GELU) {
          v = 0.5f * v * (1.0f + erff(v * 0.7071067811865476f));
          obf[(size_t)row * NOUT + col] = f2bf(v);
        } else {
          float* p = ofr + (size_t)row * NOUT + col;
          *p = v + *p;
        }
      }
    }
  }
}

extern "C" void kernel_launch(void* const* d_in, const int* in_sizes, int n_in,
                              void* d_out, int out_size, void* d_ws, size_t ws_size,
                              hipStream_t stream) {
  const float* x      = (const float*)d_in[0];
  const float* y      = (const float*)d_in[1];
  const float* g1     = (const float*)d_in[2];
  const float* b1     = (const float*)d_in[3];
  const float* rpb    = (const float*)d_in[4];
  const float* w_qkv  = (const float*)d_in[5];
  const float* b_qkv  = (const float*)d_in[6];
  const float* w_proj = (const float*)d_in[7];
  const float* b_proj = (const float*)d_in[8];
  const float* g2     = (const float*)d_in[9];
  const float* b2     = (const float*)d_in[10];
  const float* w_fc1  = (const float*)d_in[11];
  const float* b_fc1  = (const float*)d_in[12];
  const float* w_fc2  = (const float*)d_in[13];
  const float* b_fc2  = (const float*)d_in[14];
  float* out = (float*)d_out;

  u16* wsp = (u16*)d_ws;
  u16* wqkv_bf  = wsp;                       //  786432
  u16* wproj_bf = wsp + 786432;              //  131072
  u16* wfc1_bf  = wsp + 917504;              //  262144
  u16* wfc2_bf  = wsp + 1179648;             //  262144
  u16* xn2      = wsp + 1441792;             //  25690112
  u16* XYc      = wsp + 27131904;            //  12845056 (25088 x 512) XY, then concat
  u16* qkvc     = wsp + 39976960;            //  24 planes x 25088 x 64 (+ slack from old layout)
  u16* hbuf     = XYc;                       //  overlay (dead in MLP phase)

  convk<<<768, 256, 0, stream>>>(w_qkv,  wqkv_bf,  196608);
  convk<<<128, 256, 0, stream>>>(w_proj, wproj_bf, 32768);
  convk<<<256, 256, 0, stream>>>(w_fc1,  wfc1_bf,  65536);
  convk<<<256, 256, 0, stream>>>(w_fc2,  wfc2_bf,  65536);

  for (int c = 0; c < 4; ++c) {
    ln_gather<<<6272, 256, 0, stream>>>(x, y, g1, b1, XYc, c * CHUNK_ROWS);
    qkv_gemm<<<dim3(12, 196), 256, 0, stream>>>(XYc, wqkv_bf, b_qkv, qkvc);
    attn3<<<1024, 256, 0, stream>>>(qkvc, rpb, XYc, c * 512);
    proj_gemm<<<dim3(2, 196), 256, 0, stream>>>(XYc, wproj_bf, b_proj, x, out, c * CHUNK_ROWS);
  }

  ln2k<<<25088, 256, 0, stream>>>(out, g2, b2, xn2);

  for (int c = 0; c < 4; ++c) {
    mlp_gemm<256, 1024, true><<<dim3(8, 196), 256, 0, stream>>>(
        xn2 + (size_t)c * CHUNK_ROWS * 256, wfc1_bf, b_fc1, hbuf, nullptr);
    mlp_gemm<1024, 256, false><<<dim3(2, 196), 256, 0, stream>>>(
        hbuf, wfc2_bf, b_fc2, nullptr, out + (size_t)c * CHUNK_ROWS * 256);
  }
}